// Round 13
// baseline (1106.031 us; speedup 1.0000x reference)
//
#include <hip/hip_runtime.h>
#include <math.h>

#define D_    1024
#define H_    16
#define E_    64
#define DF_   4096
#define NL_   3
#define V_    32000
#define B_    2
#define LSEQ_ 2048
#define M_    (B_*LSEQ_)     // 4096 rows
#define QKVW  (3*D_)         // 3072

// wt element offsets (bf16) for per-layer transposed weights
#define OQKV  0
#define OWO   ((size_t)3072*1024)
#define OW1   ((size_t)4096*1024)
#define OW2   ((size_t)8192*1024)

typedef __attribute__((ext_vector_type(8))) short bf16x8;   // 8 bf16 = 4 VGPR (MFMA operand)
typedef __attribute__((ext_vector_type(4))) float f32x4;
typedef __attribute__((ext_vector_type(4))) unsigned short us4_t;

__device__ __forceinline__ float bfr2f(unsigned short u){ return __uint_as_float(((unsigned)u)<<16); }
__device__ __forceinline__ unsigned short f2bfr(float f){
  unsigned u = __float_as_uint(f);
  u += 0x7fffu + ((u>>16)&1u);          // RNE
  return (unsigned short)(u>>16);
}
__device__ __forceinline__ void gl_lds16(const unsigned short* g, unsigned short* l){
  __builtin_amdgcn_global_load_lds((const __attribute__((address_space(1))) void*)g,
                                   (__attribute__((address_space(3))) void*)l, 16, 0, 0);
}

// LN of a row held in a float4/thread: returns via h-write. Caller provides red[8].
__device__ __forceinline__ void row_ln_write(float4 v, const float* __restrict__ g,
                                             const float* __restrict__ b,
                                             unsigned short* __restrict__ hrow,
                                             float* red, int tid){
  const int wave = tid>>6, lane = tid&63;
  float s  = v.x+v.y+v.z+v.w;
  float s2 = v.x*v.x+v.y*v.y+v.z*v.z+v.w*v.w;
  #pragma unroll
  for (int off=1; off<64; off<<=1){ s += __shfl_xor(s,off); s2 += __shfl_xor(s2,off); }
  if (!lane){ red[wave]=s; red[4+wave]=s2; }
  __syncthreads();
  s  = red[0]+red[1]+red[2]+red[3];
  s2 = red[4]+red[5]+red[6]+red[7];
  const float mean = s*(1.f/D_);
  const float var  = s2*(1.f/D_) - mean*mean;
  const float rstd = rsqrtf(var + 1e-5f);
  float4 gg = ((const float4*)g)[tid];
  float4 bb = ((const float4*)b)[tid];
  us4_t ov;
  ov[0] = f2bfr((v.x-mean)*rstd*gg.x + bb.x);
  ov[1] = f2bfr((v.y-mean)*rstd*gg.y + bb.y);
  ov[2] = f2bfr((v.z-mean)*rstd*gg.z + bb.z);
  ov[3] = f2bfr((v.w-mean)*rstd*gg.w + bb.w);
  *(us4_t*)&hrow[tid*4] = ov;
}

// ---------------- embedding + ln1(layer0) + bias-concat fused ----------------
__global__ __launch_bounds__(256) void embed_ln_kernel(const int* __restrict__ tokens,
                                                       const float* __restrict__ tok_emb,
                                                       const float* __restrict__ pos_emb,
                                                       const float* __restrict__ g,
                                                       const float* __restrict__ b,
                                                       const float* __restrict__ bq,
                                                       const float* __restrict__ bk,
                                                       const float* __restrict__ bv,
                                                       float* __restrict__ bqkv3,
                                                       float* __restrict__ x,
                                                       unsigned short* __restrict__ h){
  __shared__ float red[8];
  const int r = blockIdx.x, tid = threadIdx.x;
  if (r < NL_*QKVW/256){               // 36 blocks also build bqkv3[3][3072]
    int i = r*256 + tid;
    int layer = i / QKVW, j = i % QKVW;
    bqkv3[i] = (j < D_) ? bq[layer*D_+j] : (j < 2*D_) ? bk[layer*D_+j-D_] : bv[layer*D_+j-2*D_];
  }
  const int l = r & (LSEQ_-1);
  const int t = tokens[r];
  float4 te = ((const float4*)(tok_emb + (size_t)t*D_))[tid];
  float4 pe = ((const float4*)(pos_emb + (size_t)l*D_))[tid];
  float4 o = {te.x+pe.x, te.y+pe.y, te.z+pe.z, te.w+pe.w};
  ((float4*)(x + (size_t)r*D_))[tid] = o;
  row_ln_write(o, g, b, h + (size_t)r*D_, red, tid);
}

// ---------------- layernorm (ln3 only) ----------------
__global__ __launch_bounds__(256) void ln_kernel(const float* __restrict__ x,
                                                 const float* __restrict__ g,
                                                 const float* __restrict__ b,
                                                 unsigned short* __restrict__ h){
  __shared__ float red[8];
  const int r = blockIdx.x, tid = threadIdx.x;
  float4 v = ((const float4*)(x + (size_t)r*D_))[tid];
  row_ln_write(v, g, b, h + (size_t)r*D_, red, tid);
}

// x += pt0+pt1+bias ; h = LN(x)*g+b   (split-K reduce for W2 + next norm fused)
__global__ __launch_bounds__(256) void reduce2_ln_kernel(float* __restrict__ x,
                                                         const float* __restrict__ pt,
                                                         const float* __restrict__ bias,
                                                         const float* __restrict__ g,
                                                         const float* __restrict__ b,
                                                         unsigned short* __restrict__ h){
  __shared__ float red[8];
  const int r = blockIdx.x, tid = threadIdx.x;
  const size_t i = ((size_t)r*D_ + tid*4);
  float4 xv = *(const float4*)(x + i);
  float4 p0 = *(const float4*)(pt + i);
  float4 p1 = *(const float4*)(pt + (size_t)M_*D_ + i);
  float4 bb = *(const float4*)(bias + tid*4);
  xv.x += p0.x + p1.x + bb.x;
  xv.y += p0.y + p1.y + bb.y;
  xv.z += p0.z + p1.z + bb.z;
  xv.w += p0.w + p1.w + bb.w;
  *(float4*)(x + i) = xv;
  row_ln_write(xv, g, b, h + (size_t)r*D_, red, tid);
}

// ---------------- per-layer mega transpose: Wq,Wk,Wv,Wo,W1,W2 -> wt sections ----------------
__global__ __launch_bounds__(256) void transpose_layer_kernel(const float* __restrict__ Wq,
                                                              const float* __restrict__ Wk,
                                                              const float* __restrict__ Wv,
                                                              const float* __restrict__ Wo,
                                                              const float* __restrict__ W1,
                                                              const float* __restrict__ W2,
                                                              unsigned short* __restrict__ wt){
  __shared__ unsigned short T[64*65];
  const int bid = blockIdx.x, tid = threadIdx.x;
  const float* W; unsigned short* dst; int N, K, n0, k0;
  if (bid < 768){        // QKV: 3 x 16x16 tiles, N=K=1024
    int z = bid>>8, t = bid&255;
    W = (z==0)?Wq:(z==1)?Wk:Wv; N=1024; K=1024;
    n0=(t&15)*64; k0=(t>>4)*64;
    dst = wt + OQKV + (size_t)z*1024*1024;
  } else if (bid < 1024){ // Wo: 16x16
    int t = bid-768; W=Wo; N=1024; K=1024;
    n0=(t&15)*64; k0=(t>>4)*64; dst = wt + OWO;
  } else if (bid < 2048){ // W1: [D][DF], N=4096,K=1024 -> 64x16
    int t = bid-1024; W=W1; N=4096; K=1024;
    n0=(t&63)*64; k0=(t>>6)*64; dst = wt + OW1;
  } else {                // W2: [DF][D], N=1024,K=4096 -> 16x64
    int t = bid-2048; W=W2; N=1024; K=4096;
    n0=(t&15)*64; k0=(t>>4)*64; dst = wt + OW2;
  }
  const int rr = tid>>4, c4 = (tid&15)*4;
  #pragma unroll
  for (int pp=0; pp<4; pp++){
    int row = pp*16 + rr;
    float4 f = *(const float4*)(W + (size_t)(k0+row)*N + n0 + c4);
    T[(c4+0)*65 + row] = f2bfr(f.x);
    T[(c4+1)*65 + row] = f2bfr(f.y);
    T[(c4+2)*65 + row] = f2bfr(f.z);
    T[(c4+3)*65 + row] = f2bfr(f.w);
  }
  __syncthreads();
  const int nr = tid>>2, kc = (tid&3)*16;
  bf16x8 o0, o1;
  #pragma unroll
  for (int j=0;j<8;j++){ o0[j] = (short)T[nr*65 + kc + j];
                         o1[j] = (short)T[nr*65 + kc + 8 + j]; }
  *(bf16x8*)&dst[(size_t)(n0+nr)*K + k0 + kc]     = o0;
  *(bf16x8*)&dst[(size_t)(n0+nr)*K + k0 + kc + 8] = o1;
}

// ---------------- plain transpose (Wout only) ----------------
__global__ __launch_bounds__(256) void transpose_kernel(const float* __restrict__ W,
                                                        unsigned short* __restrict__ WT,
                                                        int N, int K, int rowOff){
  __shared__ unsigned short T[64*65];
  const int n0 = blockIdx.x*64, k0 = blockIdx.y*64;
  const int tid = threadIdx.x;
  const int rr = tid>>4, c4 = (tid&15)*4;
  #pragma unroll
  for (int pp=0; pp<4; pp++){
    int row = pp*16 + rr;
    float4 f = *(const float4*)(W + (size_t)(k0+row)*N + n0 + c4);
    T[(c4+0)*65 + row] = f2bfr(f.x);
    T[(c4+1)*65 + row] = f2bfr(f.y);
    T[(c4+2)*65 + row] = f2bfr(f.z);
    T[(c4+3)*65 + row] = f2bfr(f.w);
  }
  __syncthreads();
  const int nr = tid>>2, kc = (tid&3)*16;
  bf16x8 o0, o1;
  #pragma unroll
  for (int j=0;j<8;j++){ o0[j] = (short)T[nr*65 + kc + j];
                         o1[j] = (short)T[nr*65 + kc + 8 + j]; }
  *(bf16x8*)&WT[(size_t)(rowOff+n0+nr)*K + k0 + kc]     = o0;
  *(bf16x8*)&WT[(size_t)(rowOff+n0+nr)*K + k0 + kc + 8] = o1;
}

// ---------------- 128^2 2-phase GEMM ----------------
// EPI 2: resid_f32 += v (Wo) ; EPI 5: split-K partial f32 store (no bias), z = blockIdx.z
template<int EPI>
__global__ __launch_bounds__(256) void gemm_bt(const unsigned short* __restrict__ A,
                                               const unsigned short* __restrict__ Bt,
                                               const float* __restrict__ bias,
                                               unsigned short* __restrict__ Cb,
                                               float* __restrict__ Cf,
                                               int K, int Klen, int ldc){
  __shared__ unsigned short As[128*64];
  __shared__ unsigned short Bs[128*64];
  const int tid = threadIdx.x;
  const int wave = tid>>6, lane = tid&63;
  const int m0 = blockIdx.x*128, n0 = blockIdx.y*128;
  const int kbase = blockIdx.z * Klen;
  const int wr = wave>>1, wc = wave&1;
  const unsigned short* Ab = A + (size_t)m0*K + kbase;
  const unsigned short* Bb = Bt + (size_t)n0*K + kbase;
  f32x4 acc[4][4] = {};
  int srow[4], sk[4];
  #pragma unroll
  for (int i=0;i<4;i++){
    int ci = i*256 + tid;
    srow[i] = ci>>3;
    sk[i]   = ((ci&7) ^ (srow[i]&7))*8;
  }
  for (int kt=0; kt<Klen; kt+=64){
    __syncthreads();
    #pragma unroll
    for (int i=0;i<4;i++){
      gl_lds16(Ab + (size_t)srow[i]*K + kt + sk[i], As + i*2048 + wave*512);
      gl_lds16(Bb + (size_t)srow[i]*K + kt + sk[i], Bs + i*2048 + wave*512);
    }
    __syncthreads();
    #pragma unroll
    for (int ks=0; ks<2; ks++){
      bf16x8 af[4], bfv[4];
      #pragma unroll
      for (int mi=0;mi<4;mi++){
        int row = wr*64 + mi*16 + (lane&15);
        int ch  = (ks*4 + (lane>>4)) ^ (row&7);
        af[mi] = *(const bf16x8*)&As[row*64 + ch*8];
      }
      #pragma unroll
      for (int ni=0;ni<4;ni++){
        int row = wc*64 + ni*16 + (lane&15);
        int ch  = (ks*4 + (lane>>4)) ^ (row&7);
        bfv[ni] = *(const bf16x8*)&Bs[row*64 + ch*8];
      }
      #pragma unroll
      for (int mi=0;mi<4;mi++)
        #pragma unroll
        for (int ni=0;ni<4;ni++)
          acc[mi][ni] = __builtin_amdgcn_mfma_f32_16x16x32_bf16(af[mi], bfv[ni], acc[mi][ni], 0,0,0);
    }
  }
  const int rq = (lane>>4)*4, cq = lane&15;
  float* Cfz = (EPI==5) ? (Cf + (size_t)blockIdx.z*M_*D_) : Cf;
  #pragma unroll
  for (int mi=0;mi<4;mi++){
    #pragma unroll
    for (int j=0;j<4;j++){
      int r = m0 + wr*64 + mi*16 + rq + j;
      #pragma unroll
      for (int ni=0;ni<4;ni++){
        int c = n0 + wc*64 + ni*16 + cq;
        if (EPI==2)      Cf[(size_t)r*D_ + c] += acc[mi][ni][j] + bias[c];
        else if (EPI==5) Cfz[(size_t)r*ldc + c] = acc[mi][ni][j];
        else             Cf[(size_t)r*ldc + c] = acc[mi][ni][j] + bias[c];
      }
    }
  }
}

// ---------------- 256^2 8-phase GEMM (T2+T3+T4+T5), N%256==0 ----------------
// EPI 0 (qkv): q-columns (blockIdx.y<4) pre-scaled by 0.125*log2(e) so attention
// runs in the exp2 domain (v_exp_f32 IS 2^x).
#define GBAR()  do{ __builtin_amdgcn_s_barrier(); __builtin_amdgcn_sched_barrier(0); }while(0)
#define GPHASE(P, STAGE_STMT, TAIL_STMT) do{                                        \
    bf16x8 afr[2][2];                                                               \
    _Pragma("unroll")                                                               \
    for (int mi=0;mi<2;mi++){                                                       \
      _Pragma("unroll")                                                             \
      for (int ks=0;ks<2;ks++){                                                     \
        int row = wr*128 + (P)*32 + mi*16 + (lane&15);                              \
        int ch  = (ks*4 + (lane>>4)) ^ (row&7);                                     \
        afr[mi][ks] = *(const bf16x8*)&Alds[row*64 + ch*8];                         \
      } }                                                                           \
    STAGE_STMT;                                                                     \
    GBAR();                                                                         \
    asm volatile("s_waitcnt lgkmcnt(0)" ::: "memory");                              \
    __builtin_amdgcn_sched_barrier(0);                                              \
    __builtin_amdgcn_s_setprio(1);                                                  \
    _Pragma("unroll")                                                               \
    for (int ks=0;ks<2;ks++){                                                       \
      _Pragma("unroll")                                                             \
      for (int mi=0;mi<2;mi++){                                                     \
        _Pragma("unroll")                                                           \
        for (int ni=0;ni<4;ni++)                                                    \
          acc[(P)*2+mi][ni] = __builtin_amdgcn_mfma_f32_16x16x32_bf16(              \
              afr[mi][ks], bfr[ni][ks], acc[(P)*2+mi][ni], 0,0,0);                  \
      } }                                                                           \
    __builtin_amdgcn_s_setprio(0);                                                  \
    __builtin_amdgcn_sched_barrier(0);                                              \
    TAIL_STMT;                                                                      \
  }while(0)

template<int EPI>
__global__ __launch_bounds__(512, 2) void gemm256(const unsigned short* __restrict__ A,
                                                  const unsigned short* __restrict__ Bt,
                                                  const float* __restrict__ bias,
                                                  unsigned short* __restrict__ Cb,
                                                  float* __restrict__ Cf,
                                                  int K, int ldc){
  __shared__ unsigned short lds[2][2][256*64];   // [buf][A/B][row*64 + chunk*8]
  const int tid = threadIdx.x, wave = tid>>6, lane = tid&63;
  const int m0 = blockIdx.x*256, n0 = blockIdx.y*256;
  const int wr = wave>>2, wc = wave&3;
  const unsigned short* Ab = A  + (size_t)m0*K;
  const unsigned short* Bb = Bt + (size_t)n0*K;
  int srow[2], scol[2];
  #pragma unroll
  for (int i=0;i<2;i++){
    int ci = i*512 + tid;
    srow[i] = ci>>3;
    scol[i] = ((ci&7) ^ (srow[i]&7))*8;
  }
  auto stageA = [&](int tbuf, int hh, int kt){
    #pragma unroll
    for (int i=0;i<2;i++)
      gl_lds16(Ab + (size_t)(hh*128+srow[i])*K + kt + scol[i],
               &lds[tbuf][0][hh*8192 + (i*512+tid)*8]);
  };
  auto stageB = [&](int tbuf, int hh, int kt){
    #pragma unroll
    for (int i=0;i<2;i++)
      gl_lds16(Bb + (size_t)(hh*128+srow[i])*K + kt + scol[i],
               &lds[tbuf][1][hh*8192 + (i*512+tid)*8]);
  };
  f32x4 acc[8][4] = {};
  const int NT = K>>6;          // callers guarantee NT >= 3
  stageB(0,0,0); stageB(0,1,0);
  stageA(0,0,0); stageA(0,1,0);
  stageB(1,0,64); stageB(1,1,64);
  asm volatile("s_waitcnt vmcnt(4)" ::: "memory");
  __builtin_amdgcn_sched_barrier(0);
  GBAR();
  for (int t=0; t<NT; ++t){
    const int buf = t&1, bufn = buf^1;
    const unsigned short* Alds = &lds[buf][0][0];
    const unsigned short* Blds = &lds[buf][1][0];
    const int ktA = (t+1)<<6, ktB = (t+2)<<6;
    const bool s1 = (t+1)<NT, s2 = (t+2)<NT;
    bf16x8 bfr[4][2];
    #pragma unroll
    for (int ni=0;ni<4;ni++)
      #pragma unroll
      for (int ks=0;ks<2;ks++){
        int row = wc*64 + ni*16 + (lane&15);
        int ch  = (ks*4 + (lane>>4)) ^ (row&7);
        bfr[ni][ks] = *(const bf16x8*)&Blds[row*64 + ch*8];
      }
    GPHASE(0, if (s1) stageA(bufn,0,ktA), ((void)0));
    GPHASE(1, if (s1) stageA(bufn,1,ktA), ((void)0));
    GPHASE(2, if (s2) stageB(buf,0,ktB), ((void)0));
    GPHASE(3, if (s2) stageB(buf,1,ktB),
           { if (s2){ asm volatile("s_waitcnt vmcnt(4)" ::: "memory"); }
             else   { asm volatile("s_waitcnt vmcnt(0)" ::: "memory"); }
             __builtin_amdgcn_sched_barrier(0);
             GBAR(); });
  }
  const int rq = (lane>>4)*4, cq = lane&15;
  const float qsc = (EPI==0 && blockIdx.y < 4) ? 0.18033688f : 1.0f;  // 0.125*log2(e)
  #pragma unroll
  for (int mi=0;mi<8;mi++){
    #pragma unroll
    for (int j=0;j<4;j++){
      int r = m0 + wr*128 + mi*16 + rq + j;
      #pragma unroll
      for (int ni=0;ni<4;ni++){
        int c = n0 + wc*64 + ni*16 + cq;
        float v = acc[mi][ni][j] + bias[c];
        if (EPI==0)      Cb[(size_t)r*ldc + c] = f2bfr(v*qsc);
        else if (EPI==1) Cb[(size_t)r*ldc + c] = f2bfr(0.5f*v*(1.f+erff(v*0.70710678f)));
        else             Cf[(size_t)r*ldc + c] = v;
      }
    }
  }
}

// ---------------- flash attention: QBLK=128, 8 waves, exp2-domain softmax ----------------
// q pre-scaled by 0.125*log2e in QKV epilogue; scores are log2-domain.
// ones-column trick: Vt rows [64,80) = 1.0; oacc[4] = softmax denominator via MFMA.
__global__ __launch_bounds__(512) void attn_kernel(const unsigned short* __restrict__ qkv,
                                                   unsigned short* __restrict__ o){
  int bid = blockIdx.x, qt, bh;
  if (bid < 256){ qt = bid & 15;        bh = bid >> 4; }
  else          { qt = 15 - (bid & 15); bh = 16 + ((bid - 256) >> 4); }
  const int b = bh>>4, h = bh&15;
  const int tid = threadIdx.x, wave = tid>>6, lane = tid&63;
  const int ql0 = qt*128;
  __shared__ unsigned short Qs[128*64];    // [q][e], 16B-chunk XOR swizzled
  __shared__ unsigned short Ks[2][64*64];  // [s][e], swizzled, double-buffered
  __shared__ unsigned short Vt[2][80*72];  // [e][s], padded; rows 64..79 = ones
  __shared__ unsigned short Ps[128*72];    // [q][s], padded (per-wave private rows)
  const size_t base = (size_t)b*LSEQ_*QKVW + (size_t)h*E_;
  const unsigned short* qb = qkv + base;
  const unsigned short* kb = qkv + base + D_;
  const unsigned short* vb = qkv + base + 2*D_;
  #pragma unroll
  for (int ii=0; ii<2; ii++){
    int i = wave + ii*8;
    int chunk = i*64 + lane, r = chunk>>3, cc = chunk&7;
    gl_lds16(qb + (size_t)(ql0 + r)*QKVW + ((cc^(r&7))*8), Qs + i*512);
  }
  // ones rows (both buffers), written once
  for (int i = tid; i < 2*16*72; i += 512){
    int bufi = (i >= 16*72);
    int rem  = i - bufi*16*72;
    Vt[bufi][(64 + rem/72)*72 + (rem%72)] = 0x3F80;   // bf16 1.0
  }
  const int kck = wave*64 + lane, kr = kck>>3, kc = kck&7;   // K-stage geometry
  gl_lds16(kb + (size_t)kr*QKVW + ((kc^(kr&7))*8), &Ks[0][wave*512]);
  {
    bf16x8 vv = *(const bf16x8*)(vb + (size_t)lane*QKVW + wave*8);
    #pragma unroll
    for (int j=0;j<8;j++) Vt[0][(wave*8+j)*72 + lane] = (unsigned short)vv[j];
  }
  __syncthreads();
  // hoist Q fragments to registers (Qs never re-read after this)
  bf16x8 qf[2];
  {
    int qrow = wave*16 + (lane&15);
    #pragma unroll
    for (int ks=0; ks<2; ks++){
      int qc = ks*4 + (lane>>4);
      qf[ks] = *(const bf16x8*)&Qs[qrow*64 + ((qc^(qrow&7))*8)];
    }
  }
  float m4[4] = {-3e38f,-3e38f,-3e38f,-3e38f};
  f32x4 oacc[5] = {};          // [4] = denominator accumulator
  const int nkv = qt*2 + 2;
  for (int t=0; t<nkv; t++){
    const int s0 = t*64, cur = t&1, nxt = cur^1;
    const bool more = (t+1) < nkv;
    bf16x8 vvn;
    if (more){
      const int s0n = s0 + 64;
      gl_lds16(kb + (size_t)(s0n + kr)*QKVW + ((kc^(kr&7))*8), &Ks[nxt][wave*512]);
      vvn = *(const bf16x8*)(vb + (size_t)(s0n + lane)*QKVW + wave*8);
    }
    __builtin_amdgcn_sched_barrier(0);
    f32x4 sacc[4] = {};
    __builtin_amdgcn_s_setprio(1);
    #pragma unroll
    for (int ks=0; ks<2; ks++){
      #pragma unroll
      for (int fc=0; fc<4; fc++){
        int krow = fc*16 + (lane&15);
        int qc = ks*4 + (lane>>4);
        bf16x8 bv = *(const bf16x8*)&Ks[cur][krow*64 + ((qc^(krow&7))*8)];
        sacc[fc] = __builtin_amdgcn_mfma_f32_16x16x32_bf16(qf[ks], bv, sacc[fc], 0,0,0);
      }
    }
    __builtin_amdgcn_s_setprio(0);
    float rm[4];
    if (s0 + 63 > ql0 + wave*16){     // diagonal region: per-element causal mask
      #pragma unroll
      for (int j=0;j<4;j++){
        int rowa = ql0 + wave*16 + (lane>>4)*4 + j;
        float mx = -3e38f;
        #pragma unroll
        for (int fc=0;fc<4;fc++){
          int cola = s0 + fc*16 + (lane&15);
          if (cola > rowa) sacc[fc][j] = -3e38f;
          mx = fmaxf(mx, sacc[fc][j]);
        }
        rm[j] = mx;
      }
    } else {                          // fully-unmasked tile: pure max scan
      #pragma unroll
      for (int j=0;j<4;j++){
        float mx = fmaxf(fmaxf(sacc[0][j], sacc[1][j]), fmaxf(sacc[2][j], sacc[3][j]));
        rm[j] = mx;
      }
    }
    #pragma unroll
    for (int off=1; off<16; off<<=1)
      #pragma unroll
      for (int j=0;j<4;j++) rm[j] = fmaxf(rm[j], __shfl_xor(rm[j], off));
    bool need = (rm[0]>m4[0]+11.5f)||(rm[1]>m4[1]+11.5f)||(rm[2]>m4[2]+11.5f)||(rm[3]>m4[3]+11.5f);
    const bool rescale = (__ballot(need) != 0ull);
    if (rescale){
      float al[4];
      #pragma unroll
      for (int j=0;j<4;j++){
        float mn = fmaxf(m4[j], rm[j]);
        al[j] = exp2f(m4[j] - mn);
        m4[j] = mn;
      }
      #pragma unroll
      for (int fc=0;fc<5;fc++)
        #pragma unroll
        for (int j=0;j<4;j++) oacc[fc][j] *= al[j];
    }
    #pragma unroll
    for (int fc=0;fc<4;fc++)
      #pragma unroll
      for (int j=0;j<4;j++){
        float pv = exp2f(sacc[fc][j] - m4[j]);
        Ps[(wave*16 + (lane>>4)*4 + j)*72 + fc*16 + (lane&15)] =
            (unsigned short)(__float_as_uint(pv)>>16);   // truncating f32->bf16
      }
    __builtin_amdgcn_s_setprio(1);
    #pragma unroll
    for (int ks=0; ks<2; ks++){
      bf16x8 ap = *(const bf16x8*)&Ps[(wave*16 + (lane&15))*72 + ks*32 + (lane>>4)*8];
      #pragma unroll
      for (int fc=0;fc<5;fc++){
        bf16x8 bv = *(const bf16x8*)&Vt[cur][(fc*16 + (lane&15))*72 + ks*32 + (lane>>4)*8];
        oacc[fc] = __builtin_amdgcn_mfma_f32_16x16x32_bf16(ap, bv, oacc[fc], 0,0,0);
      }
    }
    __builtin_amdgcn_s_setprio(0);
    if (more){
      #pragma unroll
      for (int j=0;j<8;j++) Vt[nxt][(wave*8+j)*72 + lane] = (unsigned short)vvn[j];
    }
    __syncthreads();
  }
  #pragma unroll
  for (int fc=0;fc<4;fc++)
    #pragma unroll
    for (int j=0;j<4;j++){
      int r = ql0 + wave*16 + (lane>>4)*4 + j;
      int c = h*E_ + fc*16 + (lane&15);
      o[((size_t)b*LSEQ_ + r)*D_ + c] = f2bfr(oacc[fc][j] / oacc[4][j]);
    }
}

// ---------------- launcher ----------------
extern "C" void kernel_launch(void* const* d_in, const int* in_sizes, int n_in,
                              void* d_out, int out_size, void* d_ws, size_t ws_size,
                              hipStream_t stream){
  (void)in_sizes; (void)n_in; (void)out_size;
  const int*   tokens = (const int*)d_in[0];
  const float* tok_emb= (const float*)d_in[2];
  const float* pos_emb= (const float*)d_in[3];
  const float* Wq = (const float*)d_in[4];
  const float* bq = (const float*)d_in[5];
  const float* Wk = (const float*)d_in[6];
  const float* bk = (const float*)d_in[7];
  const float* Wv = (const float*)d_in[8];
  const float* bv = (const float*)d_in[9];
  const float* Wo = (const float*)d_in[10];
  const float* bo = (const float*)d_in[11];
  const float* W1 = (const float*)d_in[12];
  const float* b1 = (const float*)d_in[13];
  const float* W2 = (const float*)d_in[14];
  const float* b2 = (const float*)d_in[15];
  const float* ln1g = (const float*)d_in[16];
  const float* ln1b = (const float*)d_in[17];
  const float* ln3g = (const float*)d_in[18];
  const float* ln3b = (const float*)d_in[19];
  const float* lnfg = (const float*)d_in[20];
  const float* lnfb = (const float*)d_in[21];
  const float* Wout = (const float*)d_in[22];
  const float* bout = (const float*)d_in[23];

  char* p = (char*)d_ws;
  float* x             = (float*)p;           p += (size_t)M_*D_*sizeof(float);
  unsigned short* h    = (unsigned short*)p;  p += (size_t)M_*D_*2;
  unsigned short* qkv  = (unsigned short*)p;  p += (size_t)M_*QKVW*2;
  unsigned short* ob   = (unsigned short*)p;  p += (size_t)M_*D_*2;
  unsigned short* ffh  = (unsigned short*)p;  p += (size_t)M_*DF_*2;
  unsigned short* wt   = (unsigned short*)p;  p += (size_t)V_*D_*2;   // layer sections + Wout
  float* bqkv3         = (float*)p;           p += (size_t)NL_*QKVW*sizeof(float);
  if ((size_t)(p - (char*)d_ws) > ws_size) return;
  // split-K partials alias qkv+ob (32 MB, both dead at W2 time)
  float* pt = (float*)qkv;

  embed_ln_kernel<<<M_, 256, 0, stream>>>(tokens, tok_emb, pos_emb, ln1g, ln1b,
                                          bq, bk, bv, bqkv3, x, h);
  for (int i=0;i<NL_;i++){
    const size_t wOff  = (size_t)i*D_*D_;
    const size_t w1Off = (size_t)i*D_*DF_;
    transpose_layer_kernel<<<3072, 256, 0, stream>>>(Wq + wOff, Wk + wOff, Wv + wOff,
                                                     Wo + wOff, W1 + w1Off, W2 + w1Off, wt);
    gemm256<0><<<dim3(M_/256, QKVW/256), 512, 0, stream>>>(h, wt + OQKV, bqkv3 + i*QKVW, qkv, nullptr, D_, QKVW);
    attn_kernel<<<512, 512, 0, stream>>>(qkv, ob);
    gemm_bt<2><<<dim3(M_/128, D_/128), 256, 0, stream>>>(ob, wt + OWO, bo + i*D_, nullptr, x, D_, D_, D_);
    ln_kernel<<<M_, 256, 0, stream>>>(x, ln3g + i*D_, ln3b + i*D_, h);
    gemm256<1><<<dim3(M_/256, DF_/256), 512, 0, stream>>>(h, wt + OW1, b1 + i*DF_, ffh, nullptr, D_, DF_);
    gemm_bt<5><<<dim3(M_/128, D_/128, 2), 256, 0, stream>>>(ffh, wt + OW2, nullptr, nullptr, pt, DF_, DF_/2, D_);
    reduce2_ln_kernel<<<M_, 256, 0, stream>>>(x, pt, b2 + i*D_,
                                              (i < NL_-1) ? ln1g + (i+1)*D_ : lnfg,
                                              (i < NL_-1) ? ln1b + (i+1)*D_ : lnfb, h);
  }
  transpose_kernel<<<dim3(V_/64, D_/64), 256, 0, stream>>>(Wout, wt, V_, D_, 0);
  gemm256<3><<<dim3(M_/256, V_/256), 512, 0, stream>>>(h, wt, bout, nullptr, (float*)d_out, D_, V_);
}

// Round 14
// 1091.709 us; speedup vs baseline: 1.0131x; 1.0131x over previous
//
#include <hip/hip_runtime.h>
#include <math.h>

#define D_    1024
#define H_    16
#define E_    64
#define DF_   4096
#define NL_   3
#define V_    32000
#define B_    2
#define LSEQ_ 2048
#define M_    (B_*LSEQ_)     // 4096 rows
#define QKVW  (3*D_)         // 3072

// wt element offsets (bf16) for per-layer transposed weights
#define OQKV  0
#define OWO   ((size_t)3072*1024)
#define OW1   ((size_t)4096*1024)
#define OW2   ((size_t)8192*1024)

typedef __attribute__((ext_vector_type(8))) short bf16x8;   // 8 bf16 = 4 VGPR (MFMA operand)
typedef __attribute__((ext_vector_type(4))) float f32x4;
typedef __attribute__((ext_vector_type(4))) unsigned short us4_t;

__device__ __forceinline__ float bfr2f(unsigned short u){ return __uint_as_float(((unsigned)u)<<16); }
__device__ __forceinline__ unsigned short f2bfr(float f){
  unsigned u = __float_as_uint(f);
  u += 0x7fffu + ((u>>16)&1u);          // RNE
  return (unsigned short)(u>>16);
}
__device__ __forceinline__ void gl_lds16(const unsigned short* g, unsigned short* l){
  __builtin_amdgcn_global_load_lds((const __attribute__((address_space(1))) void*)g,
                                   (__attribute__((address_space(3))) void*)l, 16, 0, 0);
}
// A&S 7.1.26 erf, |err| <= 1.5e-7 (<< bf16 ulp at these magnitudes)
__device__ __forceinline__ float fast_erf(float x){
  float xa = fabsf(x);
  float tt = __frcp_rn(1.f + 0.3275911f*xa);
  float poly = tt*(0.254829592f + tt*(-0.284496736f + tt*(1.421413741f +
               tt*(-1.453152027f + tt*1.061405429f))));
  float er = 1.f - poly*__expf(-xa*xa);
  return copysignf(er, x);
}

// LN of a row held in a float4/thread: returns via h-write. Caller provides red[8].
__device__ __forceinline__ void row_ln_write(float4 v, const float* __restrict__ g,
                                             const float* __restrict__ b,
                                             unsigned short* __restrict__ hrow,
                                             float* red, int tid){
  const int wave = tid>>6, lane = tid&63;
  float s  = v.x+v.y+v.z+v.w;
  float s2 = v.x*v.x+v.y*v.y+v.z*v.z+v.w*v.w;
  #pragma unroll
  for (int off=1; off<64; off<<=1){ s += __shfl_xor(s,off); s2 += __shfl_xor(s2,off); }
  if (!lane){ red[wave]=s; red[4+wave]=s2; }
  __syncthreads();
  s  = red[0]+red[1]+red[2]+red[3];
  s2 = red[4]+red[5]+red[6]+red[7];
  const float mean = s*(1.f/D_);
  const float var  = s2*(1.f/D_) - mean*mean;
  const float rstd = rsqrtf(var + 1e-5f);
  float4 gg = ((const float4*)g)[tid];
  float4 bb = ((const float4*)b)[tid];
  us4_t ov;
  ov[0] = f2bfr((v.x-mean)*rstd*gg.x + bb.x);
  ov[1] = f2bfr((v.y-mean)*rstd*gg.y + bb.y);
  ov[2] = f2bfr((v.z-mean)*rstd*gg.z + bb.z);
  ov[3] = f2bfr((v.w-mean)*rstd*gg.w + bb.w);
  *(us4_t*)&hrow[tid*4] = ov;
}

// ---------------- embedding + ln1(layer0) + bias-concat fused ----------------
__global__ __launch_bounds__(256) void embed_ln_kernel(const int* __restrict__ tokens,
                                                       const float* __restrict__ tok_emb,
                                                       const float* __restrict__ pos_emb,
                                                       const float* __restrict__ g,
                                                       const float* __restrict__ b,
                                                       const float* __restrict__ bq,
                                                       const float* __restrict__ bk,
                                                       const float* __restrict__ bv,
                                                       float* __restrict__ bqkv3,
                                                       float* __restrict__ x,
                                                       unsigned short* __restrict__ h){
  __shared__ float red[8];
  const int r = blockIdx.x, tid = threadIdx.x;
  if (r < NL_*QKVW/256){               // 36 blocks also build bqkv3[3][3072]
    int i = r*256 + tid;
    int layer = i / QKVW, j = i % QKVW;
    bqkv3[i] = (j < D_) ? bq[layer*D_+j] : (j < 2*D_) ? bk[layer*D_+j-D_] : bv[layer*D_+j-2*D_];
  }
  const int l = r & (LSEQ_-1);
  const int t = tokens[r];
  float4 te = ((const float4*)(tok_emb + (size_t)t*D_))[tid];
  float4 pe = ((const float4*)(pos_emb + (size_t)l*D_))[tid];
  float4 o = {te.x+pe.x, te.y+pe.y, te.z+pe.z, te.w+pe.w};
  ((float4*)(x + (size_t)r*D_))[tid] = o;
  row_ln_write(o, g, b, h + (size_t)r*D_, red, tid);
}

// ---------------- layernorm (ln3 only) ----------------
__global__ __launch_bounds__(256) void ln_kernel(const float* __restrict__ x,
                                                 const float* __restrict__ g,
                                                 const float* __restrict__ b,
                                                 unsigned short* __restrict__ h){
  __shared__ float red[8];
  const int r = blockIdx.x, tid = threadIdx.x;
  float4 v = ((const float4*)(x + (size_t)r*D_))[tid];
  row_ln_write(v, g, b, h + (size_t)r*D_, red, tid);
}

// x += pt0+pt1+bias ; h = LN(x)*g+b   (split-K reduce for W2 + next norm fused)
__global__ __launch_bounds__(256) void reduce2_ln_kernel(float* __restrict__ x,
                                                         const float* __restrict__ pt,
                                                         const float* __restrict__ bias,
                                                         const float* __restrict__ g,
                                                         const float* __restrict__ b,
                                                         unsigned short* __restrict__ h){
  __shared__ float red[8];
  const int r = blockIdx.x, tid = threadIdx.x;
  const size_t i = ((size_t)r*D_ + tid*4);
  float4 xv = *(const float4*)(x + i);
  float4 p0 = *(const float4*)(pt + i);
  float4 p1 = *(const float4*)(pt + (size_t)M_*D_ + i);
  float4 bb = *(const float4*)(bias + tid*4);
  xv.x += p0.x + p1.x + bb.x;
  xv.y += p0.y + p1.y + bb.y;
  xv.z += p0.z + p1.z + bb.z;
  xv.w += p0.w + p1.w + bb.w;
  *(float4*)(x + i) = xv;
  row_ln_write(xv, g, b, h + (size_t)r*D_, red, tid);
}

// ---------------- pipelined per-layer mega transpose: 4 tiles/block ----------------
// tile t: QKV t<768 (3x 16x16), Wo t<1024, W1 t<2048 (64x16), W2 t<3072 (16x64)
__global__ __launch_bounds__(256) void transpose_layer_kernel(const float* __restrict__ Wq,
                                                              const float* __restrict__ Wk,
                                                              const float* __restrict__ Wv,
                                                              const float* __restrict__ Wo,
                                                              const float* __restrict__ W1,
                                                              const float* __restrict__ W2,
                                                              unsigned short* __restrict__ wt){
  __shared__ unsigned short T[64*65];
  const int tid = threadIdx.x;
  const int rr = tid>>4, c4 = (tid&15)*4;
  const int nr = tid>>2, kc = (tid&3)*16;
  auto params = [&](int t, const float*& W, unsigned short*& dst, int& N, int& K, int& n0, int& k0){
    if (t < 768){
      int z = t>>8, tt = t&255;
      W = (z==0)?Wq:(z==1)?Wk:Wv; N=1024; K=1024;
      n0=(tt&15)*64; k0=(tt>>4)*64;
      dst = wt + OQKV + (size_t)z*1024*1024;
    } else if (t < 1024){
      int tt = t-768; W=Wo; N=1024; K=1024;
      n0=(tt&15)*64; k0=(tt>>4)*64; dst = wt + OWO;
    } else if (t < 2048){
      int tt = t-1024; W=W1; N=4096; K=1024;
      n0=(tt&63)*64; k0=(tt>>6)*64; dst = wt + OW1;
    } else {
      int tt = t-2048; W=W2; N=1024; K=4096;
      n0=(tt&15)*64; k0=(tt>>4)*64; dst = wt + OW2;
    }
  };
  auto loadRegs = [&](int t, float4* r){
    const float* W; unsigned short* dst; int N, K, n0, k0;
    params(t, W, dst, N, K, n0, k0);
    #pragma unroll
    for (int pp=0; pp<4; pp++)
      r[pp] = *(const float4*)(W + (size_t)(k0+pp*16+rr)*N + n0 + c4);
  };
  float4 r[4];
  loadRegs(blockIdx.x*4, r);
  #pragma unroll
  for (int i=0; i<4; i++){
    float4 rn[4];
    if (i<3) loadRegs(blockIdx.x*4 + i + 1, rn);   // next-tile loads in flight
    #pragma unroll
    for (int pp=0; pp<4; pp++){
      int row = pp*16 + rr;
      T[(c4+0)*65 + row] = f2bfr(r[pp].x);
      T[(c4+1)*65 + row] = f2bfr(r[pp].y);
      T[(c4+2)*65 + row] = f2bfr(r[pp].z);
      T[(c4+3)*65 + row] = f2bfr(r[pp].w);
    }
    __syncthreads();
    {
      const float* W; unsigned short* dst; int N, K, n0, k0;
      params(blockIdx.x*4 + i, W, dst, N, K, n0, k0);
      bf16x8 o0, o1;
      #pragma unroll
      for (int j=0;j<8;j++){ o0[j] = (short)T[nr*65 + kc + j];
                             o1[j] = (short)T[nr*65 + kc + 8 + j]; }
      *(bf16x8*)&dst[(size_t)(n0+nr)*K + k0 + kc]     = o0;
      *(bf16x8*)&dst[(size_t)(n0+nr)*K + k0 + kc + 8] = o1;
    }
    if (i<3){
      __syncthreads();
      #pragma unroll
      for (int pp=0; pp<4; pp++) r[pp] = rn[pp];
    }
  }
}

// ---------------- pipelined Wout transpose: 4 tiles/block, 2000 blocks ----------------
__global__ __launch_bounds__(256) void transpose_wout_kernel(const float* __restrict__ W,
                                                             unsigned short* __restrict__ WT){
  __shared__ unsigned short T[64*65];
  const int tid = threadIdx.x;
  const int rr = tid>>4, c4 = (tid&15)*4;
  const int nr = tid>>2, kc = (tid&3)*16;
  auto loadRegs = [&](int t, float4* r){
    int n0 = (t%500)*64, k0 = (t/500)*64;
    #pragma unroll
    for (int pp=0; pp<4; pp++)
      r[pp] = *(const float4*)(W + (size_t)(k0+pp*16+rr)*V_ + n0 + c4);
  };
  float4 r[4];
  loadRegs(blockIdx.x*4, r);
  #pragma unroll
  for (int i=0; i<4; i++){
    float4 rn[4];
    if (i<3) loadRegs(blockIdx.x*4 + i + 1, rn);
    #pragma unroll
    for (int pp=0; pp<4; pp++){
      int row = pp*16 + rr;
      T[(c4+0)*65 + row] = f2bfr(r[pp].x);
      T[(c4+1)*65 + row] = f2bfr(r[pp].y);
      T[(c4+2)*65 + row] = f2bfr(r[pp].z);
      T[(c4+3)*65 + row] = f2bfr(r[pp].w);
    }
    __syncthreads();
    {
      int t = blockIdx.x*4 + i;
      int n0 = (t%500)*64, k0 = (t/500)*64;
      bf16x8 o0, o1;
      #pragma unroll
      for (int j=0;j<8;j++){ o0[j] = (short)T[nr*65 + kc + j];
                             o1[j] = (short)T[nr*65 + kc + 8 + j]; }
      *(bf16x8*)&WT[(size_t)(n0+nr)*D_ + k0 + kc]     = o0;
      *(bf16x8*)&WT[(size_t)(n0+nr)*D_ + k0 + kc + 8] = o1;
    }
    if (i<3){
      __syncthreads();
      #pragma unroll
      for (int pp=0; pp<4; pp++) r[pp] = rn[pp];
    }
  }
}

// ---------------- 128^2 2-phase GEMM ----------------
// EPI 2: resid_f32 += v (Wo) ; EPI 5: split-K partial f32 store (no bias), z = blockIdx.z
template<int EPI>
__global__ __launch_bounds__(256) void gemm_bt(const unsigned short* __restrict__ A,
                                               const unsigned short* __restrict__ Bt,
                                               const float* __restrict__ bias,
                                               unsigned short* __restrict__ Cb,
                                               float* __restrict__ Cf,
                                               int K, int Klen, int ldc){
  __shared__ unsigned short As[128*64];
  __shared__ unsigned short Bs[128*64];
  const int tid = threadIdx.x;
  const int wave = tid>>6, lane = tid&63;
  const int m0 = blockIdx.x*128, n0 = blockIdx.y*128;
  const int kbase = blockIdx.z * Klen;
  const int wr = wave>>1, wc = wave&1;
  const unsigned short* Ab = A + (size_t)m0*K + kbase;
  const unsigned short* Bb = Bt + (size_t)n0*K + kbase;
  f32x4 acc[4][4] = {};
  int srow[4], sk[4];
  #pragma unroll
  for (int i=0;i<4;i++){
    int ci = i*256 + tid;
    srow[i] = ci>>3;
    sk[i]   = ((ci&7) ^ (srow[i]&7))*8;
  }
  for (int kt=0; kt<Klen; kt+=64){
    __syncthreads();
    #pragma unroll
    for (int i=0;i<4;i++){
      gl_lds16(Ab + (size_t)srow[i]*K + kt + sk[i], As + i*2048 + wave*512);
      gl_lds16(Bb + (size_t)srow[i]*K + kt + sk[i], Bs + i*2048 + wave*512);
    }
    __syncthreads();
    #pragma unroll
    for (int ks=0; ks<2; ks++){
      bf16x8 af[4], bfv[4];
      #pragma unroll
      for (int mi=0;mi<4;mi++){
        int row = wr*64 + mi*16 + (lane&15);
        int ch  = (ks*4 + (lane>>4)) ^ (row&7);
        af[mi] = *(const bf16x8*)&As[row*64 + ch*8];
      }
      #pragma unroll
      for (int ni=0;ni<4;ni++){
        int row = wc*64 + ni*16 + (lane&15);
        int ch  = (ks*4 + (lane>>4)) ^ (row&7);
        bfv[ni] = *(const bf16x8*)&Bs[row*64 + ch*8];
      }
      #pragma unroll
      for (int mi=0;mi<4;mi++)
        #pragma unroll
        for (int ni=0;ni<4;ni++)
          acc[mi][ni] = __builtin_amdgcn_mfma_f32_16x16x32_bf16(af[mi], bfv[ni], acc[mi][ni], 0,0,0);
    }
  }
  const int rq = (lane>>4)*4, cq = lane&15;
  float* Cfz = (EPI==5) ? (Cf + (size_t)blockIdx.z*M_*D_) : Cf;
  #pragma unroll
  for (int mi=0;mi<4;mi++){
    #pragma unroll
    for (int j=0;j<4;j++){
      int r = m0 + wr*64 + mi*16 + rq + j;
      #pragma unroll
      for (int ni=0;ni<4;ni++){
        int c = n0 + wc*64 + ni*16 + cq;
        if (EPI==2)      Cf[(size_t)r*D_ + c] += acc[mi][ni][j] + bias[c];
        else if (EPI==5) Cfz[(size_t)r*ldc + c] = acc[mi][ni][j];
        else             Cf[(size_t)r*ldc + c] = acc[mi][ni][j] + bias[c];
      }
    }
  }
}

// ---------------- 256^2 8-phase GEMM (T2+T3+T4+T5), N%256==0 ----------------
// EPI 0 (qkv): q-columns (blockIdx.y<4) pre-scaled by 0.125*log2(e) so attention
// runs in the exp2 domain (v_exp_f32 IS 2^x).
#define GBAR()  do{ __builtin_amdgcn_s_barrier(); __builtin_amdgcn_sched_barrier(0); }while(0)
#define GPHASE(P, STAGE_STMT, TAIL_STMT) do{                                        \
    bf16x8 afr[2][2];                                                               \
    _Pragma("unroll")                                                               \
    for (int mi=0;mi<2;mi++){                                                       \
      _Pragma("unroll")                                                             \
      for (int ks=0;ks<2;ks++){                                                     \
        int row = wr*128 + (P)*32 + mi*16 + (lane&15);                              \
        int ch  = (ks*4 + (lane>>4)) ^ (row&7);                                     \
        afr[mi][ks] = *(const bf16x8*)&Alds[row*64 + ch*8];                         \
      } }                                                                           \
    STAGE_STMT;                                                                     \
    GBAR();                                                                         \
    asm volatile("s_waitcnt lgkmcnt(0)" ::: "memory");                              \
    __builtin_amdgcn_sched_barrier(0);                                              \
    __builtin_amdgcn_s_setprio(1);                                                  \
    _Pragma("unroll")                                                               \
    for (int ks=0;ks<2;ks++){                                                       \
      _Pragma("unroll")                                                             \
      for (int mi=0;mi<2;mi++){                                                     \
        _Pragma("unroll")                                                           \
        for (int ni=0;ni<4;ni++)                                                    \
          acc[(P)*2+mi][ni] = __builtin_amdgcn_mfma_f32_16x16x32_bf16(              \
              afr[mi][ks], bfr[ni][ks], acc[(P)*2+mi][ni], 0,0,0);                  \
      } }                                                                           \
    __builtin_amdgcn_s_setprio(0);                                                  \
    __builtin_amdgcn_sched_barrier(0);                                              \
    TAIL_STMT;                                                                      \
  }while(0)

template<int EPI>
__global__ __launch_bounds__(512, 2) void gemm256(const unsigned short* __restrict__ A,
                                                  const unsigned short* __restrict__ Bt,
                                                  const float* __restrict__ bias,
                                                  unsigned short* __restrict__ Cb,
                                                  float* __restrict__ Cf,
                                                  int K, int ldc){
  __shared__ unsigned short lds[2][2][256*64];   // [buf][A/B][row*64 + chunk*8]
  const int tid = threadIdx.x, wave = tid>>6, lane = tid&63;
  const int m0 = blockIdx.x*256, n0 = blockIdx.y*256;
  const int wr = wave>>2, wc = wave&3;
  const unsigned short* Ab = A  + (size_t)m0*K;
  const unsigned short* Bb = Bt + (size_t)n0*K;
  int srow[2], scol[2];
  #pragma unroll
  for (int i=0;i<2;i++){
    int ci = i*512 + tid;
    srow[i] = ci>>3;
    scol[i] = ((ci&7) ^ (srow[i]&7))*8;
  }
  auto stageA = [&](int tbuf, int hh, int kt){
    #pragma unroll
    for (int i=0;i<2;i++)
      gl_lds16(Ab + (size_t)(hh*128+srow[i])*K + kt + scol[i],
               &lds[tbuf][0][hh*8192 + (i*512+tid)*8]);
  };
  auto stageB = [&](int tbuf, int hh, int kt){
    #pragma unroll
    for (int i=0;i<2;i++)
      gl_lds16(Bb + (size_t)(hh*128+srow[i])*K + kt + scol[i],
               &lds[tbuf][1][hh*8192 + (i*512+tid)*8]);
  };
  f32x4 acc[8][4] = {};
  const int NT = K>>6;          // callers guarantee NT >= 3
  stageB(0,0,0); stageB(0,1,0);
  stageA(0,0,0); stageA(0,1,0);
  stageB(1,0,64); stageB(1,1,64);
  asm volatile("s_waitcnt vmcnt(4)" ::: "memory");
  __builtin_amdgcn_sched_barrier(0);
  GBAR();
  for (int t=0; t<NT; ++t){
    const int buf = t&1, bufn = buf^1;
    const unsigned short* Alds = &lds[buf][0][0];
    const unsigned short* Blds = &lds[buf][1][0];
    const int ktA = (t+1)<<6, ktB = (t+2)<<6;
    const bool s1 = (t+1)<NT, s2 = (t+2)<NT;
    bf16x8 bfr[4][2];
    #pragma unroll
    for (int ni=0;ni<4;ni++)
      #pragma unroll
      for (int ks=0;ks<2;ks++){
        int row = wc*64 + ni*16 + (lane&15);
        int ch  = (ks*4 + (lane>>4)) ^ (row&7);
        bfr[ni][ks] = *(const bf16x8*)&Blds[row*64 + ch*8];
      }
    GPHASE(0, if (s1) stageA(bufn,0,ktA), ((void)0));
    GPHASE(1, if (s1) stageA(bufn,1,ktA), ((void)0));
    GPHASE(2, if (s2) stageB(buf,0,ktB), ((void)0));
    GPHASE(3, if (s2) stageB(buf,1,ktB),
           { if (s2){ asm volatile("s_waitcnt vmcnt(4)" ::: "memory"); }
             else   { asm volatile("s_waitcnt vmcnt(0)" ::: "memory"); }
             __builtin_amdgcn_sched_barrier(0);
             GBAR(); });
  }
  const int rq = (lane>>4)*4, cq = lane&15;
  const float qsc = (EPI==0 && blockIdx.y < 4) ? 0.18033688f : 1.0f;  // 0.125*log2(e)
  #pragma unroll
  for (int mi=0;mi<8;mi++){
    #pragma unroll
    for (int j=0;j<4;j++){
      int r = m0 + wr*128 + mi*16 + rq + j;
      #pragma unroll
      for (int ni=0;ni<4;ni++){
        int c = n0 + wc*64 + ni*16 + cq;
        float v = acc[mi][ni][j] + bias[c];
        if (EPI==0)      Cb[(size_t)r*ldc + c] = f2bfr(v*qsc);
        else if (EPI==1) Cb[(size_t)r*ldc + c] = f2bfr(0.5f*v*(1.f+fast_erf(v*0.70710678f)));
        else             Cf[(size_t)r*ldc + c] = v;
      }
    }
  }
}

// ---------------- flash attention: QBLK=128, 8 waves, exp2-domain softmax ----------------
// q pre-scaled by 0.125*log2e in QKV epilogue; scores are log2-domain.
// ones-column trick: Vt rows [64,80) = 1.0; oacc[4] = softmax denominator via MFMA.
__global__ __launch_bounds__(512) void attn_kernel(const unsigned short* __restrict__ qkv,
                                                   unsigned short* __restrict__ o){
  int bid = blockIdx.x, qt, bh;
  if (bid < 256){ qt = bid & 15;        bh = bid >> 4; }
  else          { qt = 15 - (bid & 15); bh = 16 + ((bid - 256) >> 4); }
  const int b = bh>>4, h = bh&15;
  const int tid = threadIdx.x, wave = tid>>6, lane = tid&63;
  const int ql0 = qt*128;
  __shared__ unsigned short Qs[128*64];    // [q][e], 16B-chunk XOR swizzled
  __shared__ unsigned short Ks[2][64*64];  // [s][e], swizzled, double-buffered
  __shared__ unsigned short Vt[2][80*72];  // [e][s], padded; rows 64..79 = ones
  __shared__ unsigned short Ps[128*72];    // [q][s], padded (per-wave private rows)
  const size_t base = (size_t)b*LSEQ_*QKVW + (size_t)h*E_;
  const unsigned short* qb = qkv + base;
  const unsigned short* kb = qkv + base + D_;
  const unsigned short* vb = qkv + base + 2*D_;
  #pragma unroll
  for (int ii=0; ii<2; ii++){
    int i = wave + ii*8;
    int chunk = i*64 + lane, r = chunk>>3, cc = chunk&7;
    gl_lds16(qb + (size_t)(ql0 + r)*QKVW + ((cc^(r&7))*8), Qs + i*512);
  }
  // ones rows (both buffers), written once
  for (int i = tid; i < 2*16*72; i += 512){
    int bufi = (i >= 16*72);
    int rem  = i - bufi*16*72;
    Vt[bufi][(64 + rem/72)*72 + (rem%72)] = 0x3F80;   // bf16 1.0
  }
  const int kck = wave*64 + lane, kr = kck>>3, kc = kck&7;   // K-stage geometry
  gl_lds16(kb + (size_t)kr*QKVW + ((kc^(kr&7))*8), &Ks[0][wave*512]);
  {
    bf16x8 vv = *(const bf16x8*)(vb + (size_t)lane*QKVW + wave*8);
    #pragma unroll
    for (int j=0;j<8;j++) Vt[0][(wave*8+j)*72 + lane] = (unsigned short)vv[j];
  }
  __syncthreads();
  // hoist Q fragments to registers (Qs never re-read after this)
  bf16x8 qf[2];
  {
    int qrow = wave*16 + (lane&15);
    #pragma unroll
    for (int ks=0; ks<2; ks++){
      int qc = ks*4 + (lane>>4);
      qf[ks] = *(const bf16x8*)&Qs[qrow*64 + ((qc^(qrow&7))*8)];
    }
  }
  float m4[4] = {-3e38f,-3e38f,-3e38f,-3e38f};
  f32x4 oacc[5] = {};          // [4] = denominator accumulator
  const int nkv = qt*2 + 2;
  for (int t=0; t<nkv; t++){
    const int s0 = t*64, cur = t&1, nxt = cur^1;
    const bool more = (t+1) < nkv;
    bf16x8 vvn;
    if (more){
      const int s0n = s0 + 64;
      gl_lds16(kb + (size_t)(s0n + kr)*QKVW + ((kc^(kr&7))*8), &Ks[nxt][wave*512]);
      vvn = *(const bf16x8*)(vb + (size_t)(s0n + lane)*QKVW + wave*8);
    }
    __builtin_amdgcn_sched_barrier(0);
    f32x4 sacc[4] = {};
    __builtin_amdgcn_s_setprio(1);
    #pragma unroll
    for (int ks=0; ks<2; ks++){
      #pragma unroll
      for (int fc=0; fc<4; fc++){
        int krow = fc*16 + (lane&15);
        int qc = ks*4 + (lane>>4);
        bf16x8 bv = *(const bf16x8*)&Ks[cur][krow*64 + ((qc^(krow&7))*8)];
        sacc[fc] = __builtin_amdgcn_mfma_f32_16x16x32_bf16(qf[ks], bv, sacc[fc], 0,0,0);
      }
    }
    __builtin_amdgcn_s_setprio(0);
    float rm[4];
    if (s0 + 63 > ql0 + wave*16){     // diagonal region: per-element causal mask
      #pragma unroll
      for (int j=0;j<4;j++){
        int rowa = ql0 + wave*16 + (lane>>4)*4 + j;
        float mx = -3e38f;
        #pragma unroll
        for (int fc=0;fc<4;fc++){
          int cola = s0 + fc*16 + (lane&15);
          if (cola > rowa) sacc[fc][j] = -3e38f;
          mx = fmaxf(mx, sacc[fc][j]);
        }
        rm[j] = mx;
      }
    } else {                          // fully-unmasked tile: pure max scan
      #pragma unroll
      for (int j=0;j<4;j++){
        float mx = fmaxf(fmaxf(sacc[0][j], sacc[1][j]), fmaxf(sacc[2][j], sacc[3][j]));
        rm[j] = mx;
      }
    }
    #pragma unroll
    for (int off=1; off<16; off<<=1)
      #pragma unroll
      for (int j=0;j<4;j++) rm[j] = fmaxf(rm[j], __shfl_xor(rm[j], off));
    bool need = (rm[0]>m4[0]+11.5f)||(rm[1]>m4[1]+11.5f)||(rm[2]>m4[2]+11.5f)||(rm[3]>m4[3]+11.5f);
    const bool rescale = (__ballot(need) != 0ull);
    if (rescale){
      float al[4];
      #pragma unroll
      for (int j=0;j<4;j++){
        float mn = fmaxf(m4[j], rm[j]);
        al[j] = exp2f(m4[j] - mn);
        m4[j] = mn;
      }
      #pragma unroll
      for (int fc=0;fc<5;fc++)
        #pragma unroll
        for (int j=0;j<4;j++) oacc[fc][j] *= al[j];
    }
    #pragma unroll
    for (int fc=0;fc<4;fc++)
      #pragma unroll
      for (int j=0;j<4;j++){
        float pv = exp2f(sacc[fc][j] - m4[j]);
        Ps[(wave*16 + (lane>>4)*4 + j)*72 + fc*16 + (lane&15)] =
            (unsigned short)(__float_as_uint(pv)>>16);   // truncating f32->bf16
      }
    __builtin_amdgcn_s_setprio(1);
    #pragma unroll
    for (int ks=0; ks<2; ks++){
      bf16x8 ap = *(const bf16x8*)&Ps[(wave*16 + (lane&15))*72 + ks*32 + (lane>>4)*8];
      #pragma unroll
      for (int fc=0;fc<5;fc++){
        bf16x8 bv = *(const bf16x8*)&Vt[cur][(fc*16 + (lane&15))*72 + ks*32 + (lane>>4)*8];
        oacc[fc] = __builtin_amdgcn_mfma_f32_16x16x32_bf16(ap, bv, oacc[fc], 0,0,0);
      }
    }
    __builtin_amdgcn_s_setprio(0);
    if (more){
      #pragma unroll
      for (int j=0;j<8;j++) Vt[nxt][(wave*8+j)*72 + lane] = (unsigned short)vvn[j];
    }
    __syncthreads();
  }
  #pragma unroll
  for (int fc=0;fc<4;fc++)
    #pragma unroll
    for (int j=0;j<4;j++){
      int r = ql0 + wave*16 + (lane>>4)*4 + j;
      int c = h*E_ + fc*16 + (lane&15);
      o[((size_t)b*LSEQ_ + r)*D_ + c] = f2bfr(oacc[fc][j] / oacc[4][j]);
    }
}

// ---------------- launcher ----------------
extern "C" void kernel_launch(void* const* d_in, const int* in_sizes, int n_in,
                              void* d_out, int out_size, void* d_ws, size_t ws_size,
                              hipStream_t stream){
  (void)in_sizes; (void)n_in; (void)out_size;
  const int*   tokens = (const int*)d_in[0];
  const float* tok_emb= (const float*)d_in[2];
  const float* pos_emb= (const float*)d_in[3];
  const float* Wq = (const float*)d_in[4];
  const float* bq = (const float*)d_in[5];
  const float* Wk = (const float*)d_in[6];
  const float* bk = (const float*)d_in[7];
  const float* Wv = (const float*)d_in[8];
  const float* bv = (const float*)d_in[9];
  const float* Wo = (const float*)d_in[10];
  const float* bo = (const float*)d_in[11];
  const float* W1 = (const float*)d_in[12];
  const float* b1 = (const float*)d_in[13];
  const float* W2 = (const float*)d_in[14];
  const float* b2 = (const float*)d_in[15];
  const float* ln1g = (const float*)d_in[16];
  const float* ln1b = (const float*)d_in[17];
  const float* ln3g = (const float*)d_in[18];
  const float* ln3b = (const float*)d_in[19];
  const float* lnfg = (const float*)d_in[20];
  const float* lnfb = (const float*)d_in[21];
  const float* Wout = (const float*)d_in[22];
  const float* bout = (const float*)d_in[23];

  char* p = (char*)d_ws;
  float* x             = (float*)p;           p += (size_t)M_*D_*sizeof(float);
  unsigned short* h    = (unsigned short*)p;  p += (size_t)M_*D_*2;
  unsigned short* qkv  = (unsigned short*)p;  p += (size_t)M_*QKVW*2;
  unsigned short* ob   = (unsigned short*)p;  p += (size_t)M_*D_*2;
  unsigned short* ffh  = (unsigned short*)p;  p += (size_t)M_*DF_*2;
  unsigned short* wt   = (unsigned short*)p;  p += (size_t)V_*D_*2;   // layer sections + Wout
  float* bqkv3         = (float*)p;           p += (size_t)NL_*QKVW*sizeof(float);
  if ((size_t)(p - (char*)d_ws) > ws_size) return;
  // split-K partials alias qkv+ob (32 MB, both dead at W2 time)
  float* pt = (float*)qkv;

  embed_ln_kernel<<<M_, 256, 0, stream>>>(tokens, tok_emb, pos_emb, ln1g, ln1b,
                                          bq, bk, bv, bqkv3, x, h);
  for (int i=0;i<NL_;i++){
    const size_t wOff  = (size_t)i*D_*D_;
    const size_t w1Off = (size_t)i*D_*DF_;
    transpose_layer_kernel<<<768, 256, 0, stream>>>(Wq + wOff, Wk + wOff, Wv + wOff,
                                                    Wo + wOff, W1 + w1Off, W2 + w1Off, wt);
    gemm256<0><<<dim3(M_/256, QKVW/256), 512, 0, stream>>>(h, wt + OQKV, bqkv3 + i*QKVW, qkv, nullptr, D_, QKVW);
    attn_kernel<<<512, 512, 0, stream>>>(qkv, ob);
    gemm_bt<2><<<dim3(M_/128, D_/128), 256, 0, stream>>>(ob, wt + OWO, bo + i*D_, nullptr, x, D_, D_, D_);
    ln_kernel<<<M_, 256, 0, stream>>>(x, ln3g + i*D_, ln3b + i*D_, h);
    gemm256<1><<<dim3(M_/256, DF_/256), 512, 0, stream>>>(h, wt + OW1, b1 + i*DF_, ffh, nullptr, D_, DF_);
    gemm_bt<5><<<dim3(M_/128, D_/128, 2), 256, 0, stream>>>(ffh, wt + OW2, nullptr, nullptr, pt, DF_, DF_/2, D_);
    reduce2_ln_kernel<<<M_, 256, 0, stream>>>(x, pt, b2 + i*D_,
                                              (i < NL_-1) ? ln1g + (i+1)*D_ : lnfg,
                                              (i < NL_-1) ? ln1b + (i+1)*D_ : lnfb, h);
  }
  transpose_wout_kernel<<<2000, 256, 0, stream>>>(Wout, wt);
  gemm256<3><<<dim3(M_/256, V_/256), 512, 0, stream>>>(h, wt, bout, nullptr, (float*)d_out, D_, V_);
}